// Round 7
// baseline (612.728 us; speedup 1.0000x reference)
//
#include <hip/hip_runtime.h>
#include <math.h>

// ---------------------------------------------------------------------------
// densityPropGRUCell: B=16, IN=U=1024.
// Round 7: occupancy-first GEMM — 128x256 tile, 8 waves of 64x64 (acc=64 regs,
// launch_bounds(512,4) => 16 waves/CU = 2 blocks/CU), 2-buffer 48KB LDS ring,
// 2 barriers/kt with counted vmcnt(3), 1D XCD-bijective grid decomposition.
// Also fixes the PAIR koffA bug from round 6 (W-half must read AT cols 1024+).
// ---------------------------------------------------------------------------

#define B_  16
#define N_  1024
#define NN_ (1024*1024)

typedef __bf16 bf16x8 __attribute__((ext_vector_type(8)));
typedef float  f32x4  __attribute__((ext_vector_type(4)));
typedef unsigned short ushort8v __attribute__((ext_vector_type(8)));

__device__ __forceinline__ unsigned short f2bf(float f) {
  union { float f; unsigned int u; } v; v.f = f;
  unsigned int r = v.u + 0x7fffu + ((v.u >> 16) & 1u);   // RNE
  return (unsigned short)(r >> 16);
}
__device__ __forceinline__ float bf2f(unsigned short h) {
  union { unsigned int u; float f; } v; v.u = ((unsigned int)h) << 16;
  return v.f;
}
__device__ __forceinline__ float f4get(const float4& v, int q) {
  return q == 0 ? v.x : (q == 1 ? v.y : (q == 2 ? v.z : v.w));
}
__device__ __forceinline__ unsigned short u4get(const ushort4& v, int q) {
  return q == 0 ? v.x : (q == 1 ? v.y : (q == 2 ? v.z : v.w));
}

__device__ __forceinline__ void gload_lds16(const void* g, void* l) {
  __builtin_amdgcn_global_load_lds((__attribute__((address_space(1))) void*)g,
                                   (__attribute__((address_space(3))) void*)l,
                                   16, 0, 0);
}

// ---------------------------------------------------------------------------
// 128x256-tile bf16 MFMA GEMM, BK=32, 512 threads = 8 waves (2M x 4N),
// wave tile 64x64 (4x4 frags of 16x16x32, acc = 64 VGPR).
//   D[m][n] = sum_k A[m][kofx + k] * B[n][k]
// LDS: 2-buffer ring x 24KB (A 8KB | B 16KB) = 48KB -> 2 blocks/CU.
// Per kt: STAGE(kt+1); vmcnt(3); barrierA; ds_reads+MFMAs; barrierB.
//   barrierB(kt-1) guarantees all waves' reads of buf((kt+1)&1) completed
//   before any wave's STAGE(kt+1) writes it (lgkm forced by MFMA deps).
// 1D grid, XCD-bijective: id->(xcd=id&7, m-tile, (n-tile,batch,pair)) so all
// 8 m-tiles sharing a B panel run on one XCD's L2.
// Swizzle (both sides): 2-row 128B super-rows, 16B slot ^= super-row&7.
// OMODE 0: raw bf16 (two-pass LDS-transposed 16B stores at col noff)
// OMODE 1: scaled bf16 epilogue; OMODE 2: scaled f32 epilogue (scalar).
// PAIR=1: (n,b,pair) decomposition; pair selects B source Bm/Bm2, +1024 on
// both koffA (A column base) and noff (out column base).
// ---------------------------------------------------------------------------
template<int OMODE, int PAIR>
__global__ __launch_bounds__(512, 4)
void gemmT(const unsigned short* __restrict__ A, int lda, long aStride, int koffA,
           const unsigned short* __restrict__ Bm, const unsigned short* __restrict__ Bm2,
           int ldb, long bStride, int K,
           void* __restrict__ Out, int ldo, long oStride, int noff,
           const float* __restrict__ act,
           const float* __restrict__ spU, const float* __restrict__ spW,
           const float* __restrict__ dU, const float* __restrict__ dW)
{
  __shared__ __align__(16) char ldsb[49152];   // 2 x 24KB ring
  // ---- XCD-bijective 1D decomposition (8 m-tiles, 4 n-tiles, 16 batches) ----
  const int id  = blockIdx.x;
  const int xcd = id & 7, loc = id >> 3;
  const int mt  = loc & 7;
  const int pidx = xcd + ((loc >> 3) << 3);
  const int nt  = pidx & 3;
  const int b   = (pidx >> 2) & 15;
  const int ps  = PAIR ? (pidx >> 6) : 0;
  const unsigned short* Bsel = (PAIR && ps) ? Bm2 : Bm;
  const int kofx = koffA + (ps ? 1024 : 0);
  const int nofx = noff  + (ps ? 1024 : 0);
  const int mbase = mt << 7;        // *128
  const int nbase = nt << 8;        // *256
  const int t = threadIdx.x, lane = t & 63, w = t >> 6;
  const int wm = w >> 2, wn = w & 3;     // 2M x 4N waves
  const int NT = K >> 5;

  f32x4 acc[4][4];
  const f32x4 zero4 = {0.f, 0.f, 0.f, 0.f};
#pragma unroll
  for (int i = 0; i < 4; i++)
#pragma unroll
    for (int j = 0; j < 4; j++) acc[i][j] = zero4;

  // ---- staging source addressing (pre-swizzled global, linear LDS dest) ----
  const int l3 = lane >> 3, l7 = lane & 7;
  const int posg = l7 ^ l3;
  const int gr = ((w * 8 + l3) << 1) + (posg >> 2);  // row 0..127 of a chunk
  const int gc = (posg & 3) << 3;                    // elem col within BK=32
  const unsigned short* Ag = A + (size_t)b * aStride + (size_t)(mbase + gr) * lda + kofx + gc;
  const unsigned short* Bg = Bsel + (size_t)b * bStride + (size_t)(nbase + gr) * ldb + gc;
  const size_t b128s = (size_t)128 * ldb;
  const int wdst = w << 10;                 // wave-uniform 1KB slot per chunk

  // ---- ds_read per-lane offset within a 1KB (16-row) frag block ----
  const int lrow = lane & 15, c4 = lane >> 4;
  const int aoff = ((lrow >> 1) << 7) + (((((lrow & 1) << 2) | c4) ^ (lrow >> 1)) << 4);
  const int abase0 = wm << 12;              // wave's 4KB of the A region
  const int bbase0 = 8192 + (wn << 12);     // B region + wave's 4KB

  auto STAGE = [&](int kt) {
    char* base = ldsb + (kt & 1) * 24576;
    const size_t ko = (size_t)kt << 5;
    gload_lds16(Ag + ko,         base + wdst);           // A: 128 rows (8KB)
    gload_lds16(Bg + ko,         base + 8192  + wdst);   // B rows 0..127
    gload_lds16(Bg + ko + b128s, base + 16384 + wdst);   // B rows 128..255
  };

  STAGE(0);
  for (int kt = 0; kt < NT; ++kt) {
    if (kt + 1 < NT) {
      STAGE(kt + 1);
      asm volatile("s_waitcnt vmcnt(3)" ::: "memory");   // STAGE(kt) done (own)
    } else {
      asm volatile("s_waitcnt vmcnt(0)" ::: "memory");
    }
    __builtin_amdgcn_sched_barrier(0);
    __builtin_amdgcn_s_barrier();                        // A: all staging done
    __builtin_amdgcn_sched_barrier(0);
    const char* pbuf = ldsb + (kt & 1) * 24576;
    bf16x8 av[4], bv[4];
#pragma unroll
    for (int mi = 0; mi < 4; mi++)
      av[mi] = *(const bf16x8*)(pbuf + abase0 + (mi << 10) + aoff);
#pragma unroll
    for (int ni = 0; ni < 4; ni++)
      bv[ni] = *(const bf16x8*)(pbuf + bbase0 + (ni << 10) + aoff);
#pragma unroll
    for (int ni = 0; ni < 4; ni++)
#pragma unroll
      for (int mi = 0; mi < 4; mi++)
        acc[mi][ni] = __builtin_amdgcn_mfma_f32_16x16x32_bf16(av[mi], bv[ni], acc[mi][ni], 0, 0, 0);
    __builtin_amdgcn_sched_barrier(0);
    __builtin_amdgcn_s_barrier();                        // B: reads done pre-overwrite
    __builtin_amdgcn_sched_barrier(0);
  }

  if (OMODE == 2) {
    const float* actb = act + b * N_;
    const float dUb = dU[b], dWb = dW[b];
#pragma unroll
    for (int mi = 0; mi < 4; mi++) {
      const int u0 = mbase + wm * 64 + mi * 16 + ((lane >> 4) << 2);
#pragma unroll
      for (int ni = 0; ni < 4; ni++) {
        const int v = nbase + wn * 64 + ni * 16 + (lane & 15);
        const float avv = actb[v];
#pragma unroll
        for (int r = 0; r < 4; r++) {
          const int u = u0 + r;
          float val = acc[mi][ni][r];
          if (u == v) val += dUb * spU[u] + dWb * spW[u];
          val *= actb[u] * avv;
          ((float*)Out)[(size_t)b * oStride + (size_t)u * ldo + v] = val;
        }
      }
    }
  } else {
    __syncthreads();                          // staging consumed; reuse ring
    unsigned short* scr = (unsigned short*)(ldsb + w * 4096);   // 4KB/wave
    const float* actb = (OMODE == 1) ? (act + b * N_) : nullptr;
    float dUb = 0.f, dWb = 0.f;
    if (OMODE == 1) { dUb = dU[b]; dWb = dW[b]; }
#pragma unroll
    for (int p = 0; p < 2; ++p) {
#pragma unroll
      for (int mi = 2 * p; mi < 2 * p + 2; ++mi) {
        const int rl0 = (mi - 2 * p) * 16 + ((lane >> 4) << 2);
#pragma unroll
        for (int ni = 0; ni < 4; ni++) {
          const int cl = ni * 16 + (lane & 15);
#pragma unroll
          for (int r = 0; r < 4; r++) {
            const int rl = rl0 + r;                     // 0..31
            float val = acc[mi][ni][r];
            if (OMODE == 1) {
              const int u = mbase + wm * 64 + mi * 16 + ((lane >> 4) << 2) + r;
              const int v = nbase + wn * 64 + cl;
              if (u == v) val += dUb * spU[u] + dWb * spW[u];
              val *= actb[u] * actb[v];
            }
            // chunk-XOR swizzle: element (rl, cl) -> chunk (cl>>3)^(rl&7)
            scr[rl * 64 + ((((cl >> 3) ^ (rl & 7))) << 3) + (cl & 7)] = f2bf(val);
          }
        }
      }
      asm volatile("s_waitcnt lgkmcnt(0)" ::: "memory");
      __builtin_amdgcn_sched_barrier(0);
      unsigned short* ob = (unsigned short*)Out + (size_t)b * oStride
          + (size_t)(mbase + wm * 64 + p * 32) * ldo + nofx + nbase + wn * 64;
#pragma unroll
      for (int pp = 0; pp < 4; pp++) {
        const int row = pp * 8 + (lane >> 3);
        const int ch = (lane & 7) ^ (row & 7);          // undo chunk swizzle
        ushort8v vv = *(const ushort8v*)&scr[row * 64 + ((lane & 7) << 3)];
        // note: scr[row*64 + slot*8] holds chunk (slot ^ (row&7)) of the row
        *(ushort8v*)(ob + (size_t)row * ldo + ch * 8) = vv;
      }
      if (p == 0) {
        asm volatile("s_waitcnt lgkmcnt(0)" ::: "memory");
        __builtin_amdgcn_sched_barrier(0);
      }
    }
  }
}

// --------------------------- small kernels ---------------------------------

__global__ void conv_bf16(const float* __restrict__ in, unsigned short* __restrict__ out, int n4)
{
  int i = blockIdx.x * 256 + threadIdx.x;
  const int stride = gridDim.x * 256;
  for (; i < n4; i += stride) {
    const float4 v = ((const float4*)in)[i];
    ushort4 o;
    o.x = f2bf(v.x); o.y = f2bf(v.y); o.z = f2bf(v.z); o.w = f2bf(v.w);
    ((ushort4*)out)[i] = o;
  }
}

// AT_g[u][k] = (k<1024 ? U_g[k][u] : W_g[k-1024][u]) as bf16. grid(32,64,3).
__global__ void build_AT(const float* __restrict__ Uz, const float* __restrict__ Wz,
                         const float* __restrict__ Ur, const float* __restrict__ Wr,
                         const float* __restrict__ Uh, const float* __restrict__ Wh,
                         unsigned short* __restrict__ AT)
{
  __shared__ float tile[32][33];
  const int g = blockIdx.z;
  const float* U = g == 0 ? Uz : (g == 1 ? Ur : Uh);
  const float* W = g == 0 ? Wz : (g == 1 ? Wr : Wh);
  const int u0  = blockIdx.x * 32;
  const int k0g = blockIdx.y * 32;
  const float* src = (k0g >= 1024) ? W : U;
  const int kloc = k0g & 1023;
  const int tx = threadIdx.x & 31, ty = threadIdx.x >> 5;
  unsigned short* out = AT + (size_t)g * N_ * 2048;
#pragma unroll
  for (int i = 0; i < 32; i += 8) tile[ty + i][tx] = src[(size_t)(kloc + ty + i) * N_ + u0 + tx];
  __syncthreads();
#pragma unroll
  for (int i = 0; i < 32; i += 8)
    out[(size_t)(u0 + ty + i) * 2048 + k0g + tx] = f2bf(tile[tx][ty + i]);
}

__global__ void softplus6(const float* a0, const float* a1, const float* a2,
                          const float* a3, const float* a4, const float* a5,
                          float* __restrict__ sp)
{
  const float* src[6] = {a0, a1, a2, a3, a4, a5};
  const int g = blockIdx.x;
  const float* s = src[g];
  for (int i = threadIdx.x; i < N_; i += 256) {
    float x = s[i];
    sp[g * N_ + i] = (x > 20.f) ? x : log1pf(expf(x));
  }
}

__global__ void scalars1(const float* __restrict__ mu, const float* __restrict__ prev,
                         const float* __restrict__ sin_, const float* __restrict__ Sst,
                         float* __restrict__ dA, float* __restrict__ dBzr)
{
  __shared__ float red[256];
  const int b = blockIdx.x;
  float s1 = 0.f, s2 = 0.f;
  for (int i = threadIdx.x; i < N_; i += 256) {
    const float m = mu[b * N_ + i];
    s1 += m * m + sin_[(size_t)b * NN_ + (size_t)i * (N_ + 1)];
    const float p = prev[b * N_ + i];
    s2 += p * p + Sst[(size_t)b * NN_ + (size_t)i * (N_ + 1)];
  }
  red[threadIdx.x] = s1; __syncthreads();
  for (int s = 128; s > 0; s >>= 1) { if (threadIdx.x < s) red[threadIdx.x] += red[threadIdx.x + s]; __syncthreads(); }
  if (threadIdx.x == 0) dA[b] = red[0];
  __syncthreads();
  red[threadIdx.x] = s2; __syncthreads();
  for (int s = 128; s > 0; s >>= 1) { if (threadIdx.x < s) red[threadIdx.x] += red[threadIdx.x + s]; __syncthreads(); }
  if (threadIdx.x == 0) dBzr[b] = red[0];
}

// ---- gate pre-activations, split-K partials (deterministic, no atomics) ----
__global__ __launch_bounds__(256)
void gate_pre2(const float* __restrict__ x1, const float* __restrict__ x2,
               const float* __restrict__ U0, const float* __restrict__ W0,
               const float* __restrict__ U1, const float* __restrict__ W1,
               float* __restrict__ Ppart)
{
  const int g  = blockIdx.z;
  const int ks = blockIdx.y;
  const int out = blockIdx.x * 256 + threadIdx.x;
  const int b = out >> 10, col = out & 1023;
  const float* x = (ks < 4) ? x1 : x2;
  const float* Wm = (g == 0) ? ((ks < 4) ? U0 : W0) : ((ks < 4) ? U1 : W1);
  const int k0 = (ks & 3) * 256;
  const float* xb = x + b * N_ + k0;
  const float* wp = Wm + (size_t)k0 * N_ + col;
  float acc = 0.f;
#pragma unroll 8
  for (int k = 0; k < 256; k++)
    acc += xb[k] * wp[(size_t)k * N_];
  Ppart[(g * 8 + ks) * (B_ * N_) + out] = acc;
}

__global__ void gate_act2(const float* __restrict__ P,
                          float* __restrict__ z, float* __restrict__ gz,
                          float* __restrict__ r, float* __restrict__ gr)
{
  const int out = blockIdx.x * 256 + threadIdx.x;
  float a0 = 0.f, a1 = 0.f;
#pragma unroll
  for (int ks = 0; ks < 8; ks++) {
    a0 += P[ks * (B_ * N_) + out];
    a1 += P[(8 + ks) * (B_ * N_) + out];
  }
  const float s0 = 1.f / (1.f + expf(-a0));
  const float s1 = 1.f / (1.f + expf(-a1));
  z[out] = s0; gz[out] = s0 * (1.f - s0);
  r[out] = s1; gr[out] = s1 * (1.f - s1);
}

__global__ __launch_bounds__(256)
void gate_pre1(const float* __restrict__ x1, const float* __restrict__ x2,
               const float* __restrict__ U0, const float* __restrict__ W0,
               float* __restrict__ Ppart)
{
  const int ks = blockIdx.y;
  const int out = blockIdx.x * 256 + threadIdx.x;
  const int b = out >> 10, col = out & 1023;
  const float* x = (ks < 4) ? x1 : x2;
  const float* Wm = (ks < 4) ? U0 : W0;
  const int k0 = (ks & 3) * 256;
  const float* xb = x + b * N_ + k0;
  const float* wp = Wm + (size_t)k0 * N_ + col;
  float acc = 0.f;
#pragma unroll 8
  for (int k = 0; k < 256; k++)
    acc += xb[k] * wp[(size_t)k * N_];
  Ppart[ks * (B_ * N_) + out] = acc;
}

__global__ void gate_act1(const float* __restrict__ P,
                          float* __restrict__ h, float* __restrict__ gh)
{
  const int out = blockIdx.x * 256 + threadIdx.x;
  float a0 = 0.f;
#pragma unroll
  for (int ks = 0; ks < 8; ks++) a0 += P[ks * (B_ * N_) + out];
  const float s = tanhf(a0);
  h[out] = s; gh[out] = 1.f - s * s;
}

__global__ void sr_csr(const float* __restrict__ prev, const float* __restrict__ r,
                       float* __restrict__ sr, float* __restrict__ csr)
{
  __shared__ float red[256];
  const int b = blockIdx.x;
  float s = 0.f;
  for (int i = threadIdx.x; i < N_; i += 256) {
    const float v = prev[b * N_ + i] * r[b * N_ + i];
    sr[b * N_ + i] = v;
    s += v * v;
  }
  red[threadIdx.x] = s; __syncthreads();
  for (int k = 128; k > 0; k >>= 1) { if (threadIdx.x < k) red[threadIdx.x] += red[threadIdx.x + k]; __syncthreads(); }
  if (threadIdx.x == 0) csr[b] = red[0];
}

// sigma_g = Sst.*Sr + p_i p_j Sr + r_i r_j Sst   (in place over Sr, bf16)
__global__ void hadamard_sg(const float* __restrict__ Sst, unsigned short* __restrict__ Sg,
                            const float* __restrict__ prev, const float* __restrict__ r)
{
  const size_t idx = ((size_t)blockIdx.x * 256 + threadIdx.x) * 4;
  const int b = (int)(idx >> 20);
  const int rem = (int)(idx & (NN_ - 1));
  const int i = rem >> 10, j0 = rem & 1023;
  const float pi = prev[b * N_ + i], ri = r[b * N_ + i];
  const float4  ss  = *(const float4*)(Sst + (size_t)b * NN_ + rem);
  const ushort4 sr4 = *(const ushort4*)(Sg + (size_t)b * NN_ + rem);
  ushort4 o;
  unsigned short* op = (unsigned short*)&o;
#pragma unroll
  for (int q = 0; q < 4; q++) {
    const float srv = bf2f(u4get(sr4, q));
    const float stv = f4get(ss, q);
    const float pj = prev[b * N_ + j0 + q];
    const float rj = r[b * N_ + j0 + q];
    op[q] = f2bf(stv * srv + pi * pj * srv + ri * rj * stv);
  }
  *(ushort4*)(Sg + (size_t)b * NN_ + rem) = o;
}

__global__ void scalars2(const unsigned short* __restrict__ Sg,
                         const float* __restrict__ csr, float* __restrict__ dBh)
{
  __shared__ float red[256];
  const int b = blockIdx.x;
  float s = 0.f;
  for (int i = threadIdx.x; i < N_; i += 256)
    s += bf2f(Sg[(size_t)b * NN_ + (size_t)i * (N_ + 1)]);
  red[threadIdx.x] = s; __syncthreads();
  for (int k = 128; k > 0; k >>= 1) { if (threadIdx.x < k) red[threadIdx.x] += red[threadIdx.x + k]; __syncthreads(); }
  if (threadIdx.x == 0) dBh[b] = red[0] + csr[b];
}

__global__ void mu_kernel(const float* __restrict__ z, const float* __restrict__ prev,
                          const float* __restrict__ h, float* __restrict__ mu_out)
{
  const int i = blockIdx.x * 256 + threadIdx.x;
  const float zz = z[i];
  mu_out[i] = zz * prev[i] + (1.f - zz) * h[i];
}

// Sigma_out = a + b - ab - abT, in place over SigOut (which holds Sigma_h).
__global__ void combine(const unsigned short* __restrict__ Sz, const float* __restrict__ Sst,
                        const float* __restrict__ z, const float* __restrict__ prev,
                        const float* __restrict__ h, float* __restrict__ SigOut)
{
  const int row = blockIdx.x;                 // 0..16383 = (b,u)
  const int b = row >> 10, u = row & 1023;
  const float zu = z[b * N_ + u], pu = prev[b * N_ + u], hu = h[b * N_ + u];
  const size_t base = (size_t)b * NN_ + (size_t)u * N_;
  const int j0 = threadIdx.x * 4;
  const ushort4 s4 = *(const ushort4*)(Sz + base + j0);
  const float4 sh = *(const float4*)(SigOut + base + j0);
  const float4 st = *(const float4*)(Sst + base + j0);
  const float4 zv = *(const float4*)(z + b * N_ + j0);
  const float4 pv = *(const float4*)(prev + b * N_ + j0);
  const float4 hv = *(const float4*)(h + b * N_ + j0);
  float o[4];
#pragma unroll
  for (int q = 0; q < 4; q++) {
    const int v = j0 + q;
    const float sz  = bf2f(u4get(s4, q));
    const float shh = f4get(sh, q);
    const float stt = f4get(st, q);
    const float zvv = f4get(zv, q);
    const float pvv = f4get(pv, q);
    const float hvv = f4get(hv, q);
    float res = sz * stt + zu * zvv * stt + pu * pvv * sz
              + sz * shh + (1.f - zu) * (1.f - zvv) * shh + hu * hvv * sz
              - sz * (pu * hvv) - sz * (hu * pvv);
    if (!isfinite(res)) res = 0.f;
    if (u == v) res = fabsf(res);
    o[q] = res;
  }
  float4 ov; ov.x = o[0]; ov.y = o[1]; ov.z = o[2]; ov.w = o[3];
  *(float4*)(SigOut + base + j0) = ov;
}

// ---------------------------------------------------------------------------

extern "C" void kernel_launch(void* const* d_in, const int* in_sizes, int n_in,
                              void* d_out, int out_size, void* d_ws, size_t ws_size,
                              hipStream_t stream)
{
  const float* mu   = (const float*)d_in[0];
  const float* sin_ = (const float*)d_in[1];
  const float* prev = (const float*)d_in[2];
  const float* Sst  = (const float*)d_in[3];
  const float* Uz = (const float*)d_in[4];  const float* uzs = (const float*)d_in[5];
  const float* Wz = (const float*)d_in[6];  const float* wzs = (const float*)d_in[7];
  const float* Ur = (const float*)d_in[8];  const float* urs = (const float*)d_in[9];
  const float* Wr = (const float*)d_in[10]; const float* wrs = (const float*)d_in[11];
  const float* Uh = (const float*)d_in[12]; const float* uhs = (const float*)d_in[13];
  const float* Wh = (const float*)d_in[14]; const float* whs = (const float*)d_in[15];

  char* ws = (char*)d_ws;
  size_t off = 0;
  auto take = [&](size_t bytes) -> char* {
    char* p = ws + off;
    off = (off + bytes + 255) & ~(size_t)255;
    return p;
  };
  unsigned short* Tcm = (unsigned short*)take((size_t)B_ * 2048 * 1024 * 2); // 64 MB
  unsigned short* Sz  = (unsigned short*)take((size_t)B_ * NN_ * 2);        // 32 MB
  unsigned short* Sg  = (unsigned short*)take((size_t)B_ * NN_ * 2);        // 32 MB
  unsigned short* AT  = (unsigned short*)take((size_t)3 * N_ * 2048 * 2);   // 12 MB
  float* Ppart = (float*)take((size_t)16 * B_ * N_ * 4);                    // 1 MB
  float* sp   = (float*)take(6 * N_ * 4);
  float* z    = (float*)take(B_ * N_ * 4);
  float* gz   = (float*)take(B_ * N_ * 4);
  float* rr   = (float*)take(B_ * N_ * 4);
  float* gr   = (float*)take(B_ * N_ * 4);
  float* h    = (float*)take(B_ * N_ * 4);
  float* gh   = (float*)take(B_ * N_ * 4);
  float* sr   = (float*)take(B_ * N_ * 4);
  float* dA   = (float*)take(64);
  float* dBzr = (float*)take(64);
  float* dBh  = (float*)take(64);
  float* csr  = (float*)take(64);
  if (off > ws_size) return;  // workspace too small (needs ~142 MB)

  float* mu_out = (float*)d_out;
  float* SigOut = (float*)d_out + (size_t)B_ * N_;
  // bf16 copies of the two big f32 inputs live in SigOut's dead region
  // (fully overwritten by the h-gate stage-2 + combine at the end).
  unsigned short* SinH = (unsigned short*)SigOut;                 // 32 MB
  unsigned short* SstH = (unsigned short*)SigOut + (size_t)B_ * NN_; // 32 MB

  const unsigned short* ATz = AT;
  const unsigned short* ATr = AT + (size_t)N_ * 2048;
  const unsigned short* ATh = AT + (size_t)2 * N_ * 2048;

  // ---- prep ----
  conv_bf16<<<2048, 256, 0, stream>>>(sin_, SinH, B_ * NN_ / 4);
  conv_bf16<<<2048, 256, 0, stream>>>(Sst,  SstH, B_ * NN_ / 4);
  softplus6<<<6, 256, 0, stream>>>(uzs, wzs, urs, wrs, uhs, whs, sp);
  scalars1<<<16, 256, 0, stream>>>(mu, prev, sin_, Sst, dA, dBzr);
  build_AT<<<dim3(32, 64, 3), 256, 0, stream>>>(Uz, Wz, Ur, Wr, Uh, Wh, AT);
  gate_pre2<<<dim3(64, 8, 2), 256, 0, stream>>>(mu, prev, Uz, Wz, Ur, Wr, Ppart);
  gate_act2<<<64, 256, 0, stream>>>(Ppart, z, gz, rr, gr);
  sr_csr<<<16, 256, 0, stream>>>(prev, rr, sr, csr);
  gate_pre1<<<dim3(64, 8), 256, 0, stream>>>(mu, sr, Uh, Wh, Ppart);
  gate_act1<<<64, 256, 0, stream>>>(Ppart, h, gh);

  const long tS = (long)2048 * 1024;

  // ---- z gate ----
  gemmT<0, 1><<<1024, 512, 0, stream>>>(ATz, 2048, 0, 0, SinH, SstH, 1024, (long)NN_, 1024,
                                        Tcm, 2048, tS, 0, nullptr, nullptr, nullptr, nullptr, nullptr);
  gemmT<1, 0><<<512, 512, 0, stream>>>(ATz, 2048, 0, 0, Tcm, nullptr, 2048, tS, 2048,
                                       Sz, 1024, (long)NN_, 0, gz, sp + 0, sp + 1024, dA, dBzr);
  // ---- r gate ----
  gemmT<0, 1><<<1024, 512, 0, stream>>>(ATr, 2048, 0, 0, SinH, SstH, 1024, (long)NN_, 1024,
                                        Tcm, 2048, tS, 0, nullptr, nullptr, nullptr, nullptr, nullptr);
  gemmT<1, 0><<<512, 512, 0, stream>>>(ATr, 2048, 0, 0, Tcm, nullptr, 2048, tS, 2048,
                                       Sg, 1024, (long)NN_, 0, gr, sp + 2048, sp + 3072, dA, dBzr);
  // ---- sigma_g (in place over Sg) ----
  hadamard_sg<<<16384, 256, 0, stream>>>(Sst, Sg, prev, rr);
  scalars2<<<16, 256, 0, stream>>>(Sg, csr, dBh);
  // ---- h gate ----
  gemmT<0, 1><<<1024, 512, 0, stream>>>(ATh, 2048, 0, 0, SinH, Sg, 1024, (long)NN_, 1024,
                                        Tcm, 2048, tS, 0, nullptr, nullptr, nullptr, nullptr, nullptr);
  gemmT<2, 0><<<512, 512, 0, stream>>>(ATh, 2048, 0, 0, Tcm, nullptr, 2048, tS, 2048,
                                       SigOut, 1024, (long)NN_, 0, gh, sp + 4096, sp + 5120, dA, dBh);
  // ---- combine ----
  mu_kernel<<<64, 256, 0, stream>>>(z, prev, h, mu_out);
  combine<<<16384, 256, 0, stream>>>(Sz, Sst, z, prev, h, SigOut);
}

// Round 8
// 568.312 us; speedup vs baseline: 1.0782x; 1.0782x over previous
//
#include <hip/hip_runtime.h>
#include <math.h>

// ---------------------------------------------------------------------------
// densityPropGRUCell: B=16, IN=U=1024.
// Round 8: m201-style 8-phase GEMM. 256x256 tile, BK=64, 8 waves (2M x 4N,
// wave tile 128x64), LDS 2 x 64KB buffers. Per K-tile 4 phases, each:
// {ds-read quadrant frags | stage 1 half-tile} barrier; lgkm0; setprio(1);
// 16 MFMA; setprio(0); barrier.  Counted vmcnt(4) at K-tile boundaries
// (2 half-tiles in flight). Staging map (derived from half free-times):
//  ph1->[t+1:B1]  ph2->[t+1:A1]  ph3->[t+2:B0]  ph4->[t+2:A0].
// ---------------------------------------------------------------------------

#define B_  16
#define N_  1024
#define NN_ (1024*1024)

typedef __bf16 bf16x8 __attribute__((ext_vector_type(8)));
typedef float  f32x4  __attribute__((ext_vector_type(4)));
typedef unsigned short ushort8v __attribute__((ext_vector_type(8)));

__device__ __forceinline__ unsigned short f2bf(float f) {
  union { float f; unsigned int u; } v; v.f = f;
  unsigned int r = v.u + 0x7fffu + ((v.u >> 16) & 1u);   // RNE
  return (unsigned short)(r >> 16);
}
__device__ __forceinline__ float bf2f(unsigned short h) {
  union { unsigned int u; float f; } v; v.u = ((unsigned int)h) << 16;
  return v.f;
}
__device__ __forceinline__ float f4get(const float4& v, int q) {
  return q == 0 ? v.x : (q == 1 ? v.y : (q == 2 ? v.z : v.w));
}
__device__ __forceinline__ unsigned short u4get(const ushort4& v, int q) {
  return q == 0 ? v.x : (q == 1 ? v.y : (q == 2 ? v.z : v.w));
}

__device__ __forceinline__ void gload_lds16(const void* g, void* l) {
  __builtin_amdgcn_global_load_lds((__attribute__((address_space(1))) void*)g,
                                   (__attribute__((address_space(3))) void*)l,
                                   16, 0, 0);
}

#define MFMA_ __builtin_amdgcn_mfma_f32_16x16x32_bf16

// ---------------------------------------------------------------------------
// D[m][n] = sum_k A[m][kofx+k] * B[n][k];  M=N=1024 per (batch, pair-slice).
// OMODE 0: raw bf16 rows at col nofx (LDS-transposed 16B stores)
// OMODE 1: scaled bf16 epilogue; OMODE 2: scaled f32 epilogue (scalar).
// PAIR=1: panel index carries ps selecting {Bm,+0} / {Bm2,+1024 on kofx,nofx}.
// ---------------------------------------------------------------------------
template<int OMODE, int PAIR>
__global__ __launch_bounds__(512)
void gemm8p(const unsigned short* __restrict__ A, int lda, long aStride, int koffA,
            const unsigned short* __restrict__ Bm, const unsigned short* __restrict__ Bm2,
            int ldb, long bStride, int K,
            void* __restrict__ Out, int ldo, long oStride, int noff,
            const float* __restrict__ act,
            const float* __restrict__ spU, const float* __restrict__ spW,
            const float* __restrict__ dU, const float* __restrict__ dW)
{
  __shared__ __align__(16) char ldsb[131072];   // 2 x (A 32KB | B 32KB)
  // ---- XCD-local decomposition: all 4 m-tiles of a B-panel on one XCD ----
  const int id = blockIdx.x;
  const int xcd = id & 7, rest = id >> 3;
  const int mt = rest & 3, pp = rest >> 2;
  const int panel = xcd + (pp << 3);            // (nt, b, ps)
  const int nt = panel & 3;
  const int b  = (panel >> 2) & 15;
  const int ps = PAIR ? (panel >> 6) : 0;
  const unsigned short* Bsel = (PAIR && ps) ? Bm2 : Bm;
  const int kofx = koffA + (ps ? 1024 : 0);
  const int nofx = noff  + (ps ? 1024 : 0);
  const int mbase = mt << 8, nbase = nt << 8;
  const int tid = threadIdx.x, lane = tid & 63, w = tid >> 6;
  const int wm = w >> 2, wn = w & 3;            // 2M x 4N waves
  const int NT = K >> 6;                        // K-tiles of 64

  f32x4 acc[8][4];
  const f32x4 zero4 = {0.f, 0.f, 0.f, 0.f};
#pragma unroll
  for (int i = 0; i < 8; i++)
#pragma unroll
    for (int j = 0; j < 4; j++) acc[i][j] = zero4;

  // ---- staging addressing (pre-swizzled global src, linear LDS dest) ----
  // half-tile = 128 rows x 64 k = 16KB = 16 x 1KB blocks; block bi = rg*2+kh.
  // wave w stages blocks {2w, 2w+1}; within a 1KB block the lane->(row,col)
  // map is the inverse of the ds_read swizzle below.
  const int l3 = lane >> 3, l7 = lane & 7;
  const int posg = l7 ^ l3;
  const int gr = (l3 << 1) + (posg >> 2);       // local row 0..15
  const int gc = (posg & 3) << 3;               // local col (elems)
  const int bi0 = w << 1, bi1 = bi0 + 1;
  const int rS0 = ((bi0 >> 1) << 4) + gr, cS0 = ((bi0 & 1) << 5) + gc;
  const int rS1 = ((bi1 >> 1) << 4) + gr, cS1 = ((bi1 & 1) << 5) + gc;
  const unsigned short* Ab = A + (size_t)b * aStride + (size_t)mbase * lda + kofx;
  const unsigned short* Bb = Bsel + (size_t)b * bStride + (size_t)nbase * ldb;
  const int d0 = w << 11, d1 = (w << 11) + 1024;   // wave-uniform byte offsets

  auto SA = [&](int tt, int h) {                // stage A half h of K-tile tt
    char* dst = ldsb + ((tt & 1) << 16) + (h << 14);
    const unsigned short* s = Ab + (size_t)(h << 7) * lda + ((size_t)tt << 6);
    gload_lds16(s + (size_t)rS0 * lda + cS0, dst + d0);
    gload_lds16(s + (size_t)rS1 * lda + cS1, dst + d1);
  };
  auto SB = [&](int tt, int h) {
    char* dst = ldsb + ((tt & 1) << 16) + 32768 + (h << 14);
    const unsigned short* s = Bb + (size_t)(h << 7) * ldb + ((size_t)tt << 6);
    gload_lds16(s + (size_t)rS0 * ldb + cS0, dst + d0);
    gload_lds16(s + (size_t)rS1 * ldb + cS1, dst + d1);
  };

  // ---- ds_read frag addressing (swizzled within 1KB blocks) ----
  const int lrow = lane & 15, c4 = lane >> 4;
  const int aoff = ((lrow >> 1) << 7) + (((((lrow & 1) << 2) | c4) ^ (lrow >> 1)) << 4);
  const int abase = wm << 14;                       // wave's A half
  const int bbase = 32768 + ((wn >> 1) << 14);      // wave's B half
  const int brg   = (wn & 1) << 2;
  auto LDA = [&](const char* pb, int mi, int ks) -> bf16x8 {
    return *(const bf16x8*)(pb + abase + (((mi << 1) + ks) << 10) + aoff);
  };
  auto LDB = [&](const char* pb, int ni, int ks) -> bf16x8 {
    return *(const bf16x8*)(pb + bbase + ((((brg + ni) << 1) + ks) << 10) + aoff);
  };

  // ---- prologue: tile0 full + tile1 {B0, A0}; wait tile0 landed ----
  SA(0, 0); SA(0, 1); SB(0, 0); SB(0, 1);
  if (NT > 1) { SB(1, 0); SA(1, 0); }
  asm volatile("s_waitcnt vmcnt(4)" ::: "memory");
  __builtin_amdgcn_sched_barrier(0);
  __builtin_amdgcn_s_barrier();
  __builtin_amdgcn_sched_barrier(0);

  bf16x8 av[4][2], bv[4][2];
  for (int kt = 0; kt < NT; ++kt) {
    const char* pb = ldsb + ((kt & 1) << 16);
    // ================= phase 1: A-q0 + B-n01 reads | stage [kt+1:B1] ======
#pragma unroll
    for (int mi = 0; mi < 4; mi++)
#pragma unroll
      for (int ks = 0; ks < 2; ks++) av[mi][ks] = LDA(pb, mi, ks);
#pragma unroll
    for (int ni = 0; ni < 2; ni++)
#pragma unroll
      for (int ks = 0; ks < 2; ks++) bv[ni][ks] = LDB(pb, ni, ks);
    if (kt + 1 < NT) SB(kt + 1, 1);
    __builtin_amdgcn_s_barrier();
    asm volatile("s_waitcnt lgkmcnt(0)" ::: "memory");
    __builtin_amdgcn_sched_barrier(0);
    __builtin_amdgcn_s_setprio(1);
#pragma unroll
    for (int ni = 0; ni < 2; ni++)
#pragma unroll
      for (int mi = 0; mi < 4; mi++) {
        acc[mi][ni] = MFMA_(av[mi][0], bv[ni][0], acc[mi][ni], 0, 0, 0);
        acc[mi][ni] = MFMA_(av[mi][1], bv[ni][1], acc[mi][ni], 0, 0, 0);
      }
    __builtin_amdgcn_s_setprio(0);
    __builtin_amdgcn_sched_barrier(0);
    __builtin_amdgcn_s_barrier();
    // ================= phase 2: B-n23 reads | stage [kt+1:A1] =============
#pragma unroll
    for (int ni = 2; ni < 4; ni++)
#pragma unroll
      for (int ks = 0; ks < 2; ks++) bv[ni][ks] = LDB(pb, ni, ks);
    if (kt + 1 < NT) SA(kt + 1, 1);
    __builtin_amdgcn_s_barrier();
    asm volatile("s_waitcnt lgkmcnt(0)" ::: "memory");
    __builtin_amdgcn_sched_barrier(0);
    __builtin_amdgcn_s_setprio(1);
#pragma unroll
    for (int ni = 2; ni < 4; ni++)
#pragma unroll
      for (int mi = 0; mi < 4; mi++) {
        acc[mi][ni] = MFMA_(av[mi][0], bv[ni][0], acc[mi][ni], 0, 0, 0);
        acc[mi][ni] = MFMA_(av[mi][1], bv[ni][1], acc[mi][ni], 0, 0, 0);
      }
    __builtin_amdgcn_s_setprio(0);
    __builtin_amdgcn_sched_barrier(0);
    __builtin_amdgcn_s_barrier();
    // ================= phase 3: A-q1 reads (overwrite av) | stage [kt+2:B0]
#pragma unroll
    for (int mi = 0; mi < 4; mi++)
#pragma unroll
      for (int ks = 0; ks < 2; ks++) av[mi][ks] = LDA(pb, 4 + mi, ks);
    if (kt + 2 < NT) SB(kt + 2, 0);
    __builtin_amdgcn_s_barrier();
    asm volatile("s_waitcnt lgkmcnt(0)" ::: "memory");
    __builtin_amdgcn_sched_barrier(0);
    __builtin_amdgcn_s_setprio(1);
#pragma unroll
    for (int ni = 0; ni < 2; ni++)
#pragma unroll
      for (int mi = 0; mi < 4; mi++) {
        acc[4 + mi][ni] = MFMA_(av[mi][0], bv[ni][0], acc[4 + mi][ni], 0, 0, 0);
        acc[4 + mi][ni] = MFMA_(av[mi][1], bv[ni][1], acc[4 + mi][ni], 0, 0, 0);
      }
    __builtin_amdgcn_s_setprio(0);
    __builtin_amdgcn_sched_barrier(0);
    __builtin_amdgcn_s_barrier();
    // ================= phase 4: stage [kt+2:A0] | boundary vmcnt ==========
    if (kt + 2 < NT) {
      SA(kt + 2, 0);
      asm volatile("s_waitcnt vmcnt(4)" ::: "memory");
    } else {
      asm volatile("s_waitcnt vmcnt(0)" ::: "memory");
    }
    __builtin_amdgcn_sched_barrier(0);
    __builtin_amdgcn_s_barrier();
    __builtin_amdgcn_sched_barrier(0);
    __builtin_amdgcn_s_setprio(1);
#pragma unroll
    for (int ni = 2; ni < 4; ni++)
#pragma unroll
      for (int mi = 0; mi < 4; mi++) {
        acc[4 + mi][ni] = MFMA_(av[mi][0], bv[ni][0], acc[4 + mi][ni], 0, 0, 0);
        acc[4 + mi][ni] = MFMA_(av[mi][1], bv[ni][1], acc[4 + mi][ni], 0, 0, 0);
      }
    __builtin_amdgcn_s_setprio(0);
    __builtin_amdgcn_sched_barrier(0);
    __builtin_amdgcn_s_barrier();
  }

  if (OMODE == 2) {
    const float* actb = act + b * N_;
    const float dUb = dU[b], dWb = dW[b];
#pragma unroll
    for (int mi = 0; mi < 8; mi++) {
      const int u0 = mbase + wm * 128 + mi * 16 + ((lane >> 4) << 2);
#pragma unroll
      for (int ni = 0; ni < 4; ni++) {
        const int v = nbase + wn * 64 + ni * 16 + (lane & 15);
        const float avv = actb[v];
#pragma unroll
        for (int r = 0; r < 4; r++) {
          const int u = u0 + r;
          float val = acc[mi][ni][r];
          if (u == v) val += dUb * spU[u] + dWb * spW[u];
          val *= actb[u] * avv;
          ((float*)Out)[(size_t)b * oStride + (size_t)u * ldo + v] = val;
        }
      }
    }
  } else {
    __syncthreads();                           // ring dead; reuse as scratch
    unsigned short* scr = (unsigned short*)(ldsb + w * 16384);  // 16KB/wave
    const float* actb = (OMODE == 1) ? (act + b * N_) : nullptr;
    float dUb = 0.f, dWb = 0.f;
    if (OMODE == 1) { dUb = dU[b]; dWb = dW[b]; }
#pragma unroll
    for (int mi = 0; mi < 8; mi++) {
      const int rl0 = mi * 16 + ((lane >> 4) << 2);
#pragma unroll
      for (int ni = 0; ni < 4; ni++) {
        const int cl = ni * 16 + (lane & 15);
#pragma unroll
        for (int r = 0; r < 4; r++) {
          const int rl = rl0 + r;
          float val = acc[mi][ni][r];
          if (OMODE == 1) {
            const int u = mbase + wm * 128 + rl, v = nbase + wn * 64 + cl;
            if (u == v) val += dUb * spU[u] + dWb * spW[u];
            val *= actb[u] * actb[v];
          }
          scr[rl * 64 + ((((cl >> 3) ^ (rl & 7))) << 3) + (cl & 7)] = f2bf(val);
        }
      }
    }
    asm volatile("s_waitcnt lgkmcnt(0)" ::: "memory");
    __builtin_amdgcn_sched_barrier(0);
    unsigned short* ob = (unsigned short*)Out + (size_t)b * oStride
        + (size_t)(mbase + wm * 128) * ldo + nofx + nbase + wn * 64;
#pragma unroll
    for (int pq = 0; pq < 16; pq++) {
      const int row = pq * 8 + (lane >> 3);
      const int ch = (lane & 7) ^ (row & 7);          // chunk held in this slot
      ushort8v vv = *(const ushort8v*)&scr[row * 64 + ((lane & 7) << 3)];
      *(ushort8v*)(ob + (size_t)row * ldo + ch * 8) = vv;
    }
  }
}

// --------------------------- small kernels ---------------------------------

__global__ void conv_bf16(const float* __restrict__ in, unsigned short* __restrict__ out, int n4)
{
  int i = blockIdx.x * 256 + threadIdx.x;
  const int stride = gridDim.x * 256;
  for (; i < n4; i += stride) {
    const float4 v = ((const float4*)in)[i];
    ushort4 o;
    o.x = f2bf(v.x); o.y = f2bf(v.y); o.z = f2bf(v.z); o.w = f2bf(v.w);
    ((ushort4*)out)[i] = o;
  }
}

// AT_g[u][k] = (k<1024 ? U_g[k][u] : W_g[k-1024][u]) as bf16. grid(32,64,3).
__global__ void build_AT(const float* __restrict__ Uz, const float* __restrict__ Wz,
                         const float* __restrict__ Ur, const float* __restrict__ Wr,
                         const float* __restrict__ Uh, const float* __restrict__ Wh,
                         unsigned short* __restrict__ AT)
{
  __shared__ float tile[32][33];
  const int g = blockIdx.z;
  const float* U = g == 0 ? Uz : (g == 1 ? Ur : Uh);
  const float* W = g == 0 ? Wz : (g == 1 ? Wr : Wh);
  const int u0  = blockIdx.x * 32;
  const int k0g = blockIdx.y * 32;
  const float* src = (k0g >= 1024) ? W : U;
  const int kloc = k0g & 1023;
  const int tx = threadIdx.x & 31, ty = threadIdx.x >> 5;
  unsigned short* out = AT + (size_t)g * N_ * 2048;
#pragma unroll
  for (int i = 0; i < 32; i += 8) tile[ty + i][tx] = src[(size_t)(kloc + ty + i) * N_ + u0 + tx];
  __syncthreads();
#pragma unroll
  for (int i = 0; i < 32; i += 8)
    out[(size_t)(u0 + ty + i) * 2048 + k0g + tx] = f2bf(tile[tx][ty + i]);
}

__global__ void softplus6(const float* a0, const float* a1, const float* a2,
                          const float* a3, const float* a4, const float* a5,
                          float* __restrict__ sp)
{
  const float* src[6] = {a0, a1, a2, a3, a4, a5};
  const int g = blockIdx.x;
  const float* s = src[g];
  for (int i = threadIdx.x; i < N_; i += 256) {
    float x = s[i];
    sp[g * N_ + i] = (x > 20.f) ? x : log1pf(expf(x));
  }
}

__global__ void scalars1(const float* __restrict__ mu, const float* __restrict__ prev,
                         const float* __restrict__ sin_, const float* __restrict__ Sst,
                         float* __restrict__ dA, float* __restrict__ dBzr)
{
  __shared__ float red[256];
  const int b = blockIdx.x;
  float s1 = 0.f, s2 = 0.f;
  for (int i = threadIdx.x; i < N_; i += 256) {
    const float m = mu[b * N_ + i];
    s1 += m * m + sin_[(size_t)b * NN_ + (size_t)i * (N_ + 1)];
    const float p = prev[b * N_ + i];
    s2 += p * p + Sst[(size_t)b * NN_ + (size_t)i * (N_ + 1)];
  }
  red[threadIdx.x] = s1; __syncthreads();
  for (int s = 128; s > 0; s >>= 1) { if (threadIdx.x < s) red[threadIdx.x] += red[threadIdx.x + s]; __syncthreads(); }
  if (threadIdx.x == 0) dA[b] = red[0];
  __syncthreads();
  red[threadIdx.x] = s2; __syncthreads();
  for (int s = 128; s > 0; s >>= 1) { if (threadIdx.x < s) red[threadIdx.x] += red[threadIdx.x + s]; __syncthreads(); }
  if (threadIdx.x == 0) dBzr[b] = red[0];
}

// ---- gate pre-activations, split-K partials (deterministic, no atomics) ----
__global__ __launch_bounds__(256)
void gate_pre2(const float* __restrict__ x1, const float* __restrict__ x2,
               const float* __restrict__ U0, const float* __restrict__ W0,
               const float* __restrict__ U1, const float* __restrict__ W1,
               float* __restrict__ Ppart)
{
  const int g  = blockIdx.z;
  const int ks = blockIdx.y;
  const int out = blockIdx.x * 256 + threadIdx.x;
  const int b = out >> 10, col = out & 1023;
  const float* x = (ks < 4) ? x1 : x2;
  const float* Wm = (g == 0) ? ((ks < 4) ? U0 : W0) : ((ks < 4) ? U1 : W1);
  const int k0 = (ks & 3) * 256;
  const float* xb = x + b * N_ + k0;
  const float* wp = Wm + (size_t)k0 * N_ + col;
  float acc = 0.f;
#pragma unroll 8
  for (int k = 0; k < 256; k++)
    acc += xb[k] * wp[(size_t)k * N_];
  Ppart[(g * 8 + ks) * (B_ * N_) + out] = acc;
}

__global__ void gate_act2(const float* __restrict__ P,
                          float* __restrict__ z, float* __restrict__ gz,
                          float* __restrict__ r, float* __restrict__ gr)
{
  const int out = blockIdx.x * 256 + threadIdx.x;
  float a0 = 0.f, a1 = 0.f;
#pragma unroll
  for (int ks = 0; ks < 8; ks++) {
    a0 += P[ks * (B_ * N_) + out];
    a1 += P[(8 + ks) * (B_ * N_) + out];
  }
  const float s0 = 1.f / (1.f + expf(-a0));
  const float s1 = 1.f / (1.f + expf(-a1));
  z[out] = s0; gz[out] = s0 * (1.f - s0);
  r[out] = s1; gr[out] = s1 * (1.f - s1);
}

__global__ __launch_bounds__(256)
void gate_pre1(const float* __restrict__ x1, const float* __restrict__ x2,
               const float* __restrict__ U0, const float* __restrict__ W0,
               float* __restrict__ Ppart)
{
  const int ks = blockIdx.y;
  const int out = blockIdx.x * 256 + threadIdx.x;
  const int b = out >> 10, col = out & 1023;
  const float* x = (ks < 4) ? x1 : x2;
  const float* Wm = (ks < 4) ? U0 : W0;
  const int k0 = (ks & 3) * 256;
  const float* xb = x + b * N_ + k0;
  const float* wp = Wm + (size_t)k0 * N_ + col;
  float acc = 0.f;
#pragma unroll 8
  for (int k = 0; k < 256; k++)
    acc += xb[k] * wp[(size_t)k * N_];
  Ppart[ks * (B_ * N_) + out] = acc;
}

__global__ void gate_act1(const float* __restrict__ P,
                          float* __restrict__ h, float* __restrict__ gh)
{
  const int out = blockIdx.x * 256 + threadIdx.x;
  float a0 = 0.f;
#pragma unroll
  for (int ks = 0; ks < 8; ks++) a0 += P[ks * (B_ * N_) + out];
  const float s = tanhf(a0);
  h[out] = s; gh[out] = 1.f - s * s;
}

__global__ void sr_csr(const float* __restrict__ prev, const float* __restrict__ r,
                       float* __restrict__ sr, float* __restrict__ csr)
{
  __shared__ float red[256];
  const int b = blockIdx.x;
  float s = 0.f;
  for (int i = threadIdx.x; i < N_; i += 256) {
    const float v = prev[b * N_ + i] * r[b * N_ + i];
    sr[b * N_ + i] = v;
    s += v * v;
  }
  red[threadIdx.x] = s; __syncthreads();
  for (int k = 128; k > 0; k >>= 1) { if (threadIdx.x < k) red[threadIdx.x] += red[threadIdx.x + k]; __syncthreads(); }
  if (threadIdx.x == 0) csr[b] = red[0];
}

// sigma_g = Sst.*Sr + p_i p_j Sr + r_i r_j Sst   (in place over Sr, bf16)
__global__ void hadamard_sg(const float* __restrict__ Sst, unsigned short* __restrict__ Sg,
                            const float* __restrict__ prev, const float* __restrict__ r)
{
  const size_t idx = ((size_t)blockIdx.x * 256 + threadIdx.x) * 4;
  const int b = (int)(idx >> 20);
  const int rem = (int)(idx & (NN_ - 1));
  const int i = rem >> 10, j0 = rem & 1023;
  const float pi = prev[b * N_ + i], ri = r[b * N_ + i];
  const float4  ss  = *(const float4*)(Sst + (size_t)b * NN_ + rem);
  const ushort4 sr4 = *(const ushort4*)(Sg + (size_t)b * NN_ + rem);
  ushort4 o;
  unsigned short* op = (unsigned short*)&o;
#pragma unroll
  for (int q = 0; q < 4; q++) {
    const float srv = bf2f(u4get(sr4, q));
    const float stv = f4get(ss, q);
    const float pj = prev[b * N_ + j0 + q];
    const float rj = r[b * N_ + j0 + q];
    op[q] = f2bf(stv * srv + pi * pj * srv + ri * rj * stv);
  }
  *(ushort4*)(Sg + (size_t)b * NN_ + rem) = o;
}

__global__ void scalars2(const unsigned short* __restrict__ Sg,
                         const float* __restrict__ csr, float* __restrict__ dBh)
{
  __shared__ float red[256];
  const int b = blockIdx.x;
  float s = 0.f;
  for (int i = threadIdx.x; i < N_; i += 256)
    s += bf2f(Sg[(size_t)b * NN_ + (size_t)i * (N_ + 1)]);
  red[threadIdx.x] = s; __syncthreads();
  for (int k = 128; k > 0; k >>= 1) { if (threadIdx.x < k) red[threadIdx.x] += red[threadIdx.x + k]; __syncthreads(); }
  if (threadIdx.x == 0) dBh[b] = red[0] + csr[b];
}

__global__ void mu_kernel(const float* __restrict__ z, const float* __restrict__ prev,
                          const float* __restrict__ h, float* __restrict__ mu_out)
{
  const int i = blockIdx.x * 256 + threadIdx.x;
  const float zz = z[i];
  mu_out[i] = zz * prev[i] + (1.f - zz) * h[i];
}

// Sigma_out = a + b - ab - abT, in place over SigOut (which holds Sigma_h).
__global__ void combine(const unsigned short* __restrict__ Sz, const float* __restrict__ Sst,
                        const float* __restrict__ z, const float* __restrict__ prev,
                        const float* __restrict__ h, float* __restrict__ SigOut)
{
  const int row = blockIdx.x;                 // 0..16383 = (b,u)
  const int b = row >> 10, u = row & 1023;
  const float zu = z[b * N_ + u], pu = prev[b * N_ + u], hu = h[b * N_ + u];
  const size_t base = (size_t)b * NN_ + (size_t)u * N_;
  const int j0 = threadIdx.x * 4;
  const ushort4 s4 = *(const ushort4*)(Sz + base + j0);
  const float4 sh = *(const float4*)(SigOut + base + j0);
  const float4 st = *(const float4*)(Sst + base + j0);
  const float4 zv = *(const float4*)(z + b * N_ + j0);
  const float4 pv = *(const float4*)(prev + b * N_ + j0);
  const float4 hv = *(const float4*)(h + b * N_ + j0);
  float o[4];
#pragma unroll
  for (int q = 0; q < 4; q++) {
    const int v = j0 + q;
    const float sz  = bf2f(u4get(s4, q));
    const float shh = f4get(sh, q);
    const float stt = f4get(st, q);
    const float zvv = f4get(zv, q);
    const float pvv = f4get(pv, q);
    const float hvv = f4get(hv, q);
    float res = sz * stt + zu * zvv * stt + pu * pvv * sz
              + sz * shh + (1.f - zu) * (1.f - zvv) * shh + hu * hvv * sz
              - sz * (pu * hvv) - sz * (hu * pvv);
    if (!isfinite(res)) res = 0.f;
    if (u == v) res = fabsf(res);
    o[q] = res;
  }
  float4 ov; ov.x = o[0]; ov.y = o[1]; ov.z = o[2]; ov.w = o[3];
  *(float4*)(SigOut + base + j0) = ov;
}

// ---------------------------------------------------------------------------

extern "C" void kernel_launch(void* const* d_in, const int* in_sizes, int n_in,
                              void* d_out, int out_size, void* d_ws, size_t ws_size,
                              hipStream_t stream)
{
  const float* mu   = (const float*)d_in[0];
  const float* sin_ = (const float*)d_in[1];
  const float* prev = (const float*)d_in[2];
  const float* Sst  = (const float*)d_in[3];
  const float* Uz = (const float*)d_in[4];  const float* uzs = (const float*)d_in[5];
  const float* Wz = (const float*)d_in[6];  const float* wzs = (const float*)d_in[7];
  const float* Ur = (const float*)d_in[8];  const float* urs = (const float*)d_in[9];
  const float* Wr = (const float*)d_in[10]; const float* wrs = (const float*)d_in[11];
  const float* Uh = (const float*)d_in[12]; const float* uhs = (const float*)d_in[13];
  const float* Wh = (const float*)d_in[14]; const float* whs = (const float*)d_in[15];

  char* ws = (char*)d_ws;
  size_t off = 0;
  auto take = [&](size_t bytes) -> char* {
    char* p = ws + off;
    off = (off + bytes + 255) & ~(size_t)255;
    return p;
  };
  unsigned short* Tcm = (unsigned short*)take((size_t)B_ * 2048 * 1024 * 2); // 64 MB
  unsigned short* Sz  = (unsigned short*)take((size_t)B_ * NN_ * 2);        // 32 MB
  unsigned short* Sg  = (unsigned short*)take((size_t)B_ * NN_ * 2);        // 32 MB
  unsigned short* AT  = (unsigned short*)take((size_t)3 * N_ * 2048 * 2);   // 12 MB
  float* Ppart = (float*)take((size_t)16 * B_ * N_ * 4);                    // 1 MB
  float* sp   = (float*)take(6 * N_ * 4);
  float* z    = (float*)take(B_ * N_ * 4);
  float* gz   = (float*)take(B_ * N_ * 4);
  float* rr   = (float*)take(B_ * N_ * 4);
  float* gr   = (float*)take(B_ * N_ * 4);
  float* h    = (float*)take(B_ * N_ * 4);
  float* gh   = (float*)take(B_ * N_ * 4);
  float* sr   = (float*)take(B_ * N_ * 4);
  float* dA   = (float*)take(64);
  float* dBzr = (float*)take(64);
  float* dBh  = (float*)take(64);
  float* csr  = (float*)take(64);
  if (off > ws_size) return;  // workspace too small (needs ~142 MB)

  float* mu_out = (float*)d_out;
  float* SigOut = (float*)d_out + (size_t)B_ * N_;
  // bf16 copies of the two big f32 inputs live in SigOut's dead region
  // (fully overwritten by the h-gate stage-2 + combine at the end).
  unsigned short* SinH = (unsigned short*)SigOut;                 // 32 MB
  unsigned short* SstH = (unsigned short*)SigOut + (size_t)B_ * NN_; // 32 MB

  const unsigned short* ATz = AT;
  const unsigned short* ATr = AT + (size_t)N_ * 2048;
  const unsigned short* ATh = AT + (size_t)2 * N_ * 2048;

  // ---- prep ----
  conv_bf16<<<2048, 256, 0, stream>>>(sin_, SinH, B_ * NN_ / 4);
  conv_bf16<<<2048, 256, 0, stream>>>(Sst,  SstH, B_ * NN_ / 4);
  softplus6<<<6, 256, 0, stream>>>(uzs, wzs, urs, wrs, uhs, whs, sp);
  scalars1<<<16, 256, 0, stream>>>(mu, prev, sin_, Sst, dA, dBzr);
  build_AT<<<dim3(32, 64, 3), 256, 0, stream>>>(Uz, Wz, Ur, Wr, Uh, Wh, AT);
  gate_pre2<<<dim3(64, 8, 2), 256, 0, stream>>>(mu, prev, Uz, Wz, Ur, Wr, Ppart);
  gate_act2<<<64, 256, 0, stream>>>(Ppart, z, gz, rr, gr);
  sr_csr<<<16, 256, 0, stream>>>(prev, rr, sr, csr);
  gate_pre1<<<dim3(64, 8), 256, 0, stream>>>(mu, sr, Uh, Wh, Ppart);
  gate_act1<<<64, 256, 0, stream>>>(Ppart, h, gh);

  const long tS = (long)2048 * 1024;

  // ---- z gate ----
  gemm8p<0, 1><<<512, 512, 0, stream>>>(ATz, 2048, 0, 0, SinH, SstH, 1024, (long)NN_, 1024,
                                        Tcm, 2048, tS, 0, nullptr, nullptr, nullptr, nullptr, nullptr);
  gemm8p<1, 0><<<256, 512, 0, stream>>>(ATz, 2048, 0, 0, Tcm, nullptr, 2048, tS, 2048,
                                        Sz, 1024, (long)NN_, 0, gz, sp + 0, sp + 1024, dA, dBzr);
  // ---- r gate ----
  gemm8p<0, 1><<<512, 512, 0, stream>>>(ATr, 2048, 0, 0, SinH, SstH, 1024, (long)NN_, 1024,
                                        Tcm, 2048, tS, 0, nullptr, nullptr, nullptr, nullptr, nullptr);
  gemm8p<1, 0><<<256, 512, 0, stream>>>(ATr, 2048, 0, 0, Tcm, nullptr, 2048, tS, 2048,
                                        Sg, 1024, (long)NN_, 0, gr, sp + 2048, sp + 3072, dA, dBzr);
  // ---- sigma_g (in place over Sg) ----
  hadamard_sg<<<16384, 256, 0, stream>>>(Sst, Sg, prev, rr);
  scalars2<<<16, 256, 0, stream>>>(Sg, csr, dBh);
  // ---- h gate ----
  gemm8p<0, 1><<<512, 512, 0, stream>>>(ATh, 2048, 0, 0, SinH, Sg, 1024, (long)NN_, 1024,
                                        Tcm, 2048, tS, 0, nullptr, nullptr, nullptr, nullptr, nullptr);
  gemm8p<2, 0><<<256, 512, 0, stream>>>(ATh, 2048, 0, 0, Tcm, nullptr, 2048, tS, 2048,
                                        SigOut, 1024, (long)NN_, 0, gh, sp + 4096, sp + 5120, dA, dBh);
  // ---- combine ----
  mu_kernel<<<64, 256, 0, stream>>>(z, prev, h, mu_out);
  combine<<<16384, 256, 0, stream>>>(Sz, Sst, z, prev, h, SigOut);
}